// Round 22
// baseline (347.581 us; speedup 1.0000x reference)
//
#include <hip/hip_runtime.h>
#include <hip/hip_bf16.h>
#include <math.h>

// Problem constants: N=100000, E=600000, D=128, H=4, F=32, L=3

__device__ __forceinline__ float leaky02(float x) {
    return x >= 0.f ? x : 0.2f * x;
}
__device__ __forceinline__ float leaky01(float x) {
    return x >= 0.f ? x : 0.01f * x;
}

// bf16 helpers (round-to-nearest-even)
__device__ __forceinline__ unsigned short f2bf(float f) {
    unsigned u = __float_as_uint(f);
    unsigned r = u + 0x7FFFu + ((u >> 16) & 1u);
    return (unsigned short)(r >> 16);
}
__device__ __forceinline__ float bf2f(unsigned short s) {
    return __uint_as_float(((unsigned)s) << 16);
}

typedef __attribute__((ext_vector_type(8))) short bf16x8;
typedef __attribute__((ext_vector_type(8))) unsigned short u16x8;
typedef __attribute__((ext_vector_type(4))) float f32x4;

// ---------------------------------------------------------------------------
// Fused init: deg[i]=1 + W split into bf16 hi/lo, PACKED IN FRAGMENT ORDER:
// packed index p = ((kk*8 + c)*64 + lane)*8 + j  <-  W[(c*16+(lane&15))*128
// + kk*32 + (lane>>4)*8 + j]. Wave B-fragment load = base + lane*16B.
__global__ __launch_bounds__(256) void init_split_kernel(
    int* __restrict__ deg, int N, const float* __restrict__ W,
    short* __restrict__ Wh, short* __restrict__ Wl, int n)
{
    int i = blockIdx.x * 256 + threadIdx.x;
    if (i < N) deg[i] = 1;
    if (i < n) {
        int l    = i >> 14;          // layer (0,1)
        int p    = i & 16383;
        int j    = p & 7;
        int lane = (p >> 3) & 63;
        int c    = (p >> 9) & 7;
        int kk   = p >> 12;
        int mr   = lane & 15;
        int quad = lane >> 4;
        int row  = c * 16 + mr;
        int d    = kk * 32 + quad * 8 + j;
        float f = W[(size_t)l * 16384 + row * 128 + d];
        unsigned short hi = f2bf(f);
        Wh[i] = (short)hi;
        Wl[i] = (short)f2bf(f - bf2f(hi));
    }
}

// Mext[r][d] per layer: r 0..3 = Wt@Al head r, r 4..7 = Wt@Ar, r 8..15 = 0.
__global__ __launch_bounds__(128) void mlr_prep_kernel(
    const float* __restrict__ fc_W, const float* __restrict__ attn_l,
    const float* __restrict__ attn_r, short* __restrict__ Mh,
    short* __restrict__ Ml)
{
    int l = blockIdx.x;                       // 0,1 -> layers 1,2
    const float* W  = fc_W + (size_t)(l + 1) * 16384;
    const float* al = attn_l + (l + 1) * 128;
    const float* ar = attn_r + (l + 1) * 128;
    short* mh = Mh + (size_t)l * 16 * 128;
    short* ml = Ml + (size_t)l * 16 * 128;
    int d = threadIdx.x;
#pragma unroll
    for (int r = 0; r < 8; ++r) {
        int hh = r & 3;
        const float* av = (r < 4) ? al : ar;
        float s = 0.f;
        for (int f = 0; f < 32; ++f)
            s += W[(size_t)(hh * 32 + f) * 128 + d] * av[hh * 32 + f];
        unsigned short hi = f2bf(s);
        mh[r * 128 + d] = (short)hi;
        ml[r * 128 + d] = (short)f2bf(s - bf2f(hi));
    }
#pragma unroll
    for (int r = 8; r < 16; ++r) { mh[r * 128 + d] = 0; ml[r * 128 + d] = 0; }
}

// slot[i] = old count (>=1 because self loop holds slot 0)
__global__ __launch_bounds__(256) void deg_count_slot_kernel(
    const int* __restrict__ dst, int* __restrict__ deg,
    int* __restrict__ slot, int E)
{
    int i = blockIdx.x * 256 + threadIdx.x;
    if (i < E) slot[i] = atomicAdd(&deg[dst[i]], 1);
}

#define SCAN_TILE 1024

__global__ __launch_bounds__(256) void scanA_kernel(
    const int* __restrict__ deg, int* __restrict__ bsum, int N)
{
    __shared__ int ws[4];
    int b = blockIdx.x, t = threadIdx.x;
    int base = b * SCAN_TILE + t * 4;
    int s = 0;
#pragma unroll
    for (int k = 0; k < 4; ++k) {
        int i = base + k;
        if (i < N) s += deg[i];
    }
#pragma unroll
    for (int m = 32; m >= 1; m >>= 1) s += __shfl_xor(s, m, 64);
    if ((t & 63) == 0) ws[t >> 6] = s;
    __syncthreads();
    if (t == 0) bsum[b] = ws[0] + ws[1] + ws[2] + ws[3];
}

__global__ __launch_bounds__(1024) void scanB_kernel(
    int* __restrict__ bsum, int* __restrict__ bpre, int* __restrict__ rowp,
    int NB, int N)
{
    __shared__ int sh[1024];
    int t = threadIdx.x;
    int v = (t < NB) ? bsum[t] : 0;
    sh[t] = v;
    __syncthreads();
    for (int off = 1; off < 1024; off <<= 1) {
        int u = (t >= off) ? sh[t - off] : 0;
        __syncthreads();
        sh[t] += u;
        __syncthreads();
    }
    if (t < NB) bpre[t] = sh[t] - v;          // exclusive prefix
    if (t == 1023) rowp[N] = sh[1023];        // total
}

// scanC also writes the self-loop entry: col[rowp[i]] = i (slot 0).
__global__ __launch_bounds__(256) void scanC_kernel(
    const int* __restrict__ deg, const int* __restrict__ bpre,
    int* __restrict__ rowp, int* __restrict__ col, int N)
{
    __shared__ int sh[256];
    int b = blockIdx.x, t = threadIdx.x;
    int base = b * SCAN_TILE + t * 4;
    int v[4];
#pragma unroll
    for (int k = 0; k < 4; ++k) {
        int i = base + k;
        v[k] = (i < N) ? deg[i] : 0;
    }
    int tsum = v[0] + v[1] + v[2] + v[3];
    sh[t] = tsum;
    __syncthreads();
    for (int off = 1; off < 256; off <<= 1) {
        int u = (t >= off) ? sh[t - off] : 0;
        __syncthreads();
        sh[t] += u;
        __syncthreads();
    }
    int pre = bpre[b] + sh[t] - tsum;
#pragma unroll
    for (int k = 0; k < 4; ++k) {
        int i = base + k;
        if (i < N) {
            rowp[i] = pre;
            col[pre] = i;   // self loop at slot 0
        }
        pre += v[k];
    }
}

// atomic-free scatter: position fully determined by rowp + recorded slot
__global__ __launch_bounds__(256) void scatter2_kernel(
    const int* __restrict__ src, const int* __restrict__ dst,
    const int* __restrict__ slot, const int* __restrict__ rowp,
    int* __restrict__ col, int E)
{
    int i = blockIdx.x * 256 + threadIdx.x;
    if (i < E) col[rowp[dst[i]] + slot[i]] = src[i];
}

// ---------------------------------------------------------------------------
// Layer-0 rank-1 precompute
__global__ __launch_bounds__(128) void rank1_prep_kernel(
    const float* __restrict__ lW, const float* __restrict__ lb,
    const float* __restrict__ W0, const float* __restrict__ al,
    const float* __restrict__ ar, float* __restrict__ c1,
    float* __restrict__ c2, float* __restrict__ prm)
{
    int j = threadIdx.x;
    float s1 = 0.f, s2 = 0.f;
    for (int d = 0; d < 128; ++d) {
        float wv = W0[j * 128 + d];
        s1 += lW[d] * wv;
        s2 += lb[d] * wv;
    }
    c1[j] = s1; c2[j] = s2;
    __shared__ float sh1[128], sh2[128], sh3[128], sh4[128];
    sh1[j] = s1 * al[j]; sh2[j] = s2 * al[j];
    sh3[j] = s1 * ar[j]; sh4[j] = s2 * ar[j];
    __syncthreads();
    if (j < 4) {
        float p = 0.f, q = 0.f, r = 0.f, s = 0.f;
        for (int f = 0; f < 32; ++f) {
            p += sh1[j * 32 + f]; q += sh2[j * 32 + f];
            r += sh3[j * 32 + f]; s += sh4[j * 32 + f];
        }
        prm[j] = p; prm[4 + j] = q; prm[8 + j] = r; prm[12 + j] = s;
    }
}

// h0 (bf16) = w[n]*c1[j] + c2[j]; el0/er0 from rank-1 params.
__global__ __launch_bounds__(256) void rank1_apply_kernel(
    const float* __restrict__ w, const float* __restrict__ c1,
    const float* __restrict__ c2, const float* __restrict__ prm,
    unsigned short* __restrict__ hb, float* __restrict__ el,
    float* __restrict__ er, int N)
{
    int i = blockIdx.x * 256 + threadIdx.x;
    int n = i >> 5, k = i & 31;
    if (n >= N) return;
    float wn = w[n];
    float4 a = *reinterpret_cast<const float4*>(&c1[k * 4]);
    float4 b = *reinterpret_cast<const float4*>(&c2[k * 4]);
    ushort4 o;
    o.x = f2bf(wn * a.x + b.x);
    o.y = f2bf(wn * a.y + b.y);
    o.z = f2bf(wn * a.z + b.z);
    o.w = f2bf(wn * a.w + b.w);
    *reinterpret_cast<ushort4*>(&hb[(size_t)n * 128 + k * 4]) = o;
    if (k == 0) {
        float4 pl = *reinterpret_cast<const float4*>(&prm[0]);
        float4 ql = *reinterpret_cast<const float4*>(&prm[4]);
        float4 pr = *reinterpret_cast<const float4*>(&prm[8]);
        float4 qr = *reinterpret_cast<const float4*>(&prm[12]);
        float4 e1 = make_float4(wn * pl.x + ql.x, wn * pl.y + ql.y,
                                wn * pl.z + ql.z, wn * pl.w + ql.w);
        float4 e2 = make_float4(wn * pr.x + qr.x, wn * pr.y + qr.y,
                                wn * pr.z + qr.z, wn * pr.w + qr.w);
        *reinterpret_cast<float4*>(&el[(size_t)n * 4]) = e1;
        *reinterpret_cast<float4*>(&er[(size_t)n * 4]) = e2;
    }
}

// ---------------------------------------------------------------------------
// MFMA bf16 GEMM (layers 1,2) + fused el/er tile — 32 rows/wave,
// FRAGMENT-PACKED W *and* FRAGMENT-PACKED x (written by agg): every A and
// B load is base + lane*16B = one coalesced 1 KB transaction.
// x packed layout: ((b16*4 + kk)*64 + quad*16 + mr)*8 + j, b16 = row>>4.
__global__ __launch_bounds__(256) void gemm_mfma_kernel(
    const unsigned short* __restrict__ xb, const short* __restrict__ Wh,
    const short* __restrict__ Wl, const short* __restrict__ Mh,
    const short* __restrict__ Ml, unsigned short* __restrict__ hb,
    float* __restrict__ el, float* __restrict__ er, int N)
{
    const int lane = threadIdx.x & 63;
    const int wv   = threadIdx.x >> 6;
    const int m0   = blockIdx.x * 128 + wv * 32;  // 32 rows per wave
    const int mr   = lane & 15;
    const int quad = lane >> 4;
    const int b0   = blockIdx.x * 8 + wv * 2;     // 16-row block indices
    const int b1   = b0 + 1;

    f32x4 acc0[8], acc1[8], acce0, acce1;
#pragma unroll
    for (int c = 0; c < 8; ++c) {
        acc0[c] = (f32x4){0.f, 0.f, 0.f, 0.f};
        acc1[c] = (f32x4){0.f, 0.f, 0.f, 0.f};
    }
    acce0 = (f32x4){0.f, 0.f, 0.f, 0.f};
    acce1 = (f32x4){0.f, 0.f, 0.f, 0.f};

#pragma unroll
    for (int kk = 0; kk < 4; ++kk) {
        // packed x: A fragment = one coalesced load
        bf16x8 a0 = *reinterpret_cast<const bf16x8*>(
            xb + ((size_t)(b0 * 4 + kk) * 64 + lane) * 8);
        bf16x8 a1 = *reinterpret_cast<const bf16x8*>(
            xb + ((size_t)(b1 * 4 + kk) * 64 + lane) * 8);

        const int kb = kk * 32 + quad * 8;
        // packed W: fragment (kk,c) lives at ((kk*8+c)*64 + lane)*8
        bf16x8 bh[8], bl[8];
#pragma unroll
        for (int c = 0; c < 8; ++c) {
            const size_t wo = (size_t)((kk * 8 + c) * 64 + lane) * 8;
            bh[c] = *reinterpret_cast<const bf16x8*>(Wh + wo);
            bl[c] = *reinterpret_cast<const bf16x8*>(Wl + wo);
        }
        bf16x8 eh = *reinterpret_cast<const bf16x8*>(Mh + (size_t)mr * 128 + kb);
        bf16x8 eo = *reinterpret_cast<const bf16x8*>(Ml + (size_t)mr * 128 + kb);
#pragma unroll
        for (int c = 0; c < 8; ++c) {
            acc0[c] = __builtin_amdgcn_mfma_f32_16x16x32_bf16(a0, bh[c], acc0[c], 0, 0, 0);
            acc0[c] = __builtin_amdgcn_mfma_f32_16x16x32_bf16(a0, bl[c], acc0[c], 0, 0, 0);
            acc1[c] = __builtin_amdgcn_mfma_f32_16x16x32_bf16(a1, bh[c], acc1[c], 0, 0, 0);
            acc1[c] = __builtin_amdgcn_mfma_f32_16x16x32_bf16(a1, bl[c], acc1[c], 0, 0, 0);
        }
        acce0 = __builtin_amdgcn_mfma_f32_16x16x32_bf16(a0, eh, acce0, 0, 0, 0);
        acce0 = __builtin_amdgcn_mfma_f32_16x16x32_bf16(a0, eo, acce0, 0, 0, 0);
        acce1 = __builtin_amdgcn_mfma_f32_16x16x32_bf16(a1, eh, acce1, 0, 0, 0);
        acce1 = __builtin_amdgcn_mfma_f32_16x16x32_bf16(a1, eo, acce1, 0, 0, 0);
    }

#pragma unroll
    for (int i = 0; i < 4; ++i) {
        int rowA = m0 + quad * 4 + i;
        if (rowA < N) {
            unsigned short* hp = hb + (size_t)rowA * 128 + mr;
#pragma unroll
            for (int c = 0; c < 8; ++c) hp[c * 16] = f2bf(acc0[c][i]);
            if (mr < 4)       el[(size_t)rowA * 4 + mr]       = acce0[i];
            else if (mr < 8)  er[(size_t)rowA * 4 + (mr - 4)] = acce0[i];
        }
        int rowB = m0 + 16 + quad * 4 + i;
        if (rowB < N) {
            unsigned short* hp = hb + (size_t)rowB * 128 + mr;
#pragma unroll
            for (int c = 0; c < 8; ++c) hp[c * 16] = f2bf(acc1[c][i]);
            if (mr < 4)       el[(size_t)rowB * 4 + mr]       = acce1[i];
            else if (mr < 8)  er[(size_t)rowB * 4 + (mr - 4)] = acce1[i];
        }
    }
}

// ---------------------------------------------------------------------------
// SINGLE-PASS fused online-softmax aggregation + epilogue (R17 structure).
// last=0: x written FRAGMENT-PACKED for the next gemm's coalesced A loads.
__global__ __launch_bounds__(256) void agg_fused_kernel(
    const unsigned short* __restrict__ hb, const float* __restrict__ el,
    const float* __restrict__ er, const int* __restrict__ rowp,
    const int* __restrict__ col, const float* __restrict__ bias,
    unsigned short* __restrict__ xout, const float* __restrict__ pW,
    const float* __restrict__ pb, float* __restrict__ logits,
    int N, int last)
{
    const int lane = threadIdx.x & 63;
    const int q    = lane >> 4;
    const int l16  = lane & 15;
    const int v    = blockIdx.x * 16 + (threadIdx.x >> 6) * 4 + q;
    if (v >= N) return;   // reductions below stay within the 16-lane quarter

    const int r0 = rowp[v], r1 = rowp[v + 1];   // r1 > r0 (self loop)
    const int head = l16 >> 2;       // head for this lane's 8 features
    const int f0   = l16 * 8;        // feature base 0..120
    const float erq = er[(size_t)v * 4 + head];

    float m = -INFINITY, s = 0.f;
    float acc[8];
#pragma unroll
    for (int k = 0; k < 8; ++k) acc[k] = 0.f;

    // prime the pipeline with edge r0
    int   u_cur  = col[r0];
    float el_cur = el[(size_t)u_cur * 4 + head];
    u16x8 hv_cur = *reinterpret_cast<const u16x8*>(&hb[(size_t)u_cur * 128 + f0]);

    for (int j = r0; j < r1; ++j) {
        // issue next edge's loads before this edge's compute
        int jn = (j + 1 < r1) ? (j + 1) : j;
        int   u_nxt  = col[jn];
        float el_nxt = el[(size_t)u_nxt * 4 + head];
        u16x8 hv_nxt = *reinterpret_cast<const u16x8*>(&hb[(size_t)u_nxt * 128 + f0]);

        float e  = leaky02(el_cur + erq);
        float nm = fmaxf(m, e);
        float sc = __expf(m - nm);   // 0 on first edge (m=-inf)
        float p  = __expf(e - nm);
        s = s * sc + p;
#pragma unroll
        for (int k = 0; k < 8; ++k) acc[k] = acc[k] * sc + p * bf2f(hv_cur[k]);
        m = nm;

        u_cur = u_nxt; el_cur = el_nxt; hv_cur = hv_nxt;
    }
    const float is = 1.f / s;

    float4 b0 = *reinterpret_cast<const float4*>(&bias[f0]);
    float4 b1 = *reinterpret_cast<const float4*>(&bias[f0 + 4]);
    const float bb[8] = {b0.x, b0.y, b0.z, b0.w, b1.x, b1.y, b1.z, b1.w};

    if (last) {
        float4 p0 = *reinterpret_cast<const float4*>(&pW[f0]);
        float4 p1 = *reinterpret_cast<const float4*>(&pW[f0 + 4]);
        const float pp[8] = {p0.x, p0.y, p0.z, p0.w, p1.x, p1.y, p1.z, p1.w};
        float part = 0.f;
#pragma unroll
        for (int k = 0; k < 8; ++k) part += (acc[k] * is + bb[k]) * pp[k];
#pragma unroll
        for (int d = 1; d <= 8; d <<= 1) part += __shfl_xor(part, d, 64);
        if (l16 == 0) logits[v] = part + pb[0];
    } else {
        u16x8 o;
#pragma unroll
        for (int k = 0; k < 8; ++k) o[k] = f2bf(leaky01(acc[k] * is + bb[k]));
        // fragment-packed store: b16 = v>>4, kk = l16>>2, quad = l16&3
        const int b16 = v >> 4, mr = v & 15;
        const size_t off = ((size_t)(b16 * 4 + (l16 >> 2)) * 64
                            + (l16 & 3) * 16 + mr) * 8;
        *reinterpret_cast<u16x8*>(&xout[off]) = o;
    }
}

// ---------------------------------------------------------------------------
extern "C" void kernel_launch(void* const* d_in, const int* in_sizes, int n_in,
                              void* d_out, int out_size, void* d_ws, size_t ws_size,
                              hipStream_t stream)
{
    const float* weights = (const float*)d_in[0];
    const float* lin_W   = (const float*)d_in[1];
    const float* lin_b   = (const float*)d_in[2];
    const float* fc_W    = (const float*)d_in[3];
    const float* attn_l  = (const float*)d_in[4];
    const float* attn_r  = (const float*)d_in[5];
    const float* conv_b  = (const float*)d_in[6];
    const float* pred_W  = (const float*)d_in[7];
    const float* pred_b  = (const float*)d_in[8];
    const int*   src     = (const int*)d_in[9];
    const int*   dst     = (const int*)d_in[10];

    const int N = in_sizes[0];
    const int E = in_sizes[9];
    const int NB = (N + SCAN_TILE - 1) / SCAN_TILE;
    const int NPAD = ((N + 127) / 128) * 128;   // gemm tile coverage

    // workspace layout (16B-aligned sections)
    unsigned short* xb = (unsigned short*)d_ws;                    // NPAD*128 bf16 (packed)
    unsigned short* hb = xb + (size_t)NPAD * 128;                  // N*128 bf16
    float* el  = (float*)(hb + (size_t)N * 128);                   // N*4
    float* er  = el + (size_t)N * 4;                               // N*4
    float* c1  = er + (size_t)N * 4;                               // 128
    float* c2  = c1 + 128;                                         // 128
    float* prm = c2 + 128;                                         // 16
    short* Whs = (short*)(prm + 16);                               // 2*16384 bf16 (packed)
    short* Wls = Whs + 2 * 16384;                                  // 2*16384 bf16 (packed)
    short* Mhs = Wls + 2 * 16384;                                  // 2*2048 bf16 (Mext hi)
    short* Mls = Mhs + 2 * 2048;                                   // 2*2048 bf16 (Mext lo)
    int*   deg  = (int*)(Mls + 2 * 2048);                          // N
    int*   rowp = deg + N;                                         // N+1
    int*   slot = rowp + (N + 1);                                  // E
    int*   col  = slot + E;                                        // E+N
    int*   bsum = col + (E + N);                                   // NB
    int*   bpre = bsum + NB;                                       // NB

    // CSR build + packed W split (fresh every call: ws is re-poisoned)
    init_split_kernel<<<(N + 255) / 256, 256, 0, stream>>>(
        deg, N, fc_W + 16384, Whs, Wls, 2 * 16384);
    mlr_prep_kernel<<<2, 128, 0, stream>>>(fc_W, attn_l, attn_r, Mhs, Mls);
    deg_count_slot_kernel<<<(E + 255) / 256, 256, 0, stream>>>(dst, deg, slot, E);
    scanA_kernel<<<NB, 256, 0, stream>>>(deg, bsum, N);
    scanB_kernel<<<1, 1024, 0, stream>>>(bsum, bpre, rowp, NB, N);
    scanC_kernel<<<NB, 256, 0, stream>>>(deg, bpre, rowp, col, N);
    scatter2_kernel<<<(E + 255) / 256, 256, 0, stream>>>(src, dst, slot, rowp, col, E);

    // Layer 0 via rank-1 identity
    rank1_prep_kernel<<<1, 128, 0, stream>>>(lin_W, lin_b, fc_W, attn_l, attn_r,
                                             c1, c2, prm);
    rank1_apply_kernel<<<((size_t)N * 32 + 255) / 256, 256, 0, stream>>>(
        weights, c1, c2, prm, hb, el, er, N);
    agg_fused_kernel<<<(N + 15) / 16, 256, 0, stream>>>(
        hb, el, er, rowp, col, conv_b, xb, pred_W, pred_b, (float*)d_out, N, 0);

    // Layers 1, 2 (MFMA bf16 gemm, packed W + packed x, fused el/er)
    for (int l = 1; l < 3; ++l) {
        gemm_mfma_kernel<<<(N + 127) / 128, 256, 0, stream>>>(
            xb, Whs + (size_t)(l - 1) * 16384, Wls + (size_t)(l - 1) * 16384,
            Mhs + (size_t)(l - 1) * 2048, Mls + (size_t)(l - 1) * 2048,
            hb, el, er, N);
        agg_fused_kernel<<<(N + 15) / 16, 256, 0, stream>>>(
            hb, el, er, rowp, col, conv_b + l * 128, xb, pred_W, pred_b,
            (float*)d_out, N, l == 2 ? 1 : 0);
    }
}

// Round 23
// 344.432 us; speedup vs baseline: 1.0091x; 1.0091x over previous
//
#include <hip/hip_runtime.h>
#include <hip/hip_bf16.h>
#include <math.h>

// Problem constants: N=100000, E=600000, D=128, H=4, F=32, L=3

__device__ __forceinline__ float leaky02(float x) {
    return x >= 0.f ? x : 0.2f * x;
}
__device__ __forceinline__ float leaky01(float x) {
    return x >= 0.f ? x : 0.01f * x;
}

// bf16 helpers (round-to-nearest-even)
__device__ __forceinline__ unsigned short f2bf(float f) {
    unsigned u = __float_as_uint(f);
    unsigned r = u + 0x7FFFu + ((u >> 16) & 1u);
    return (unsigned short)(r >> 16);
}
__device__ __forceinline__ float bf2f(unsigned short s) {
    return __uint_as_float(((unsigned)s) << 16);
}

typedef __attribute__((ext_vector_type(8))) short bf16x8;
typedef __attribute__((ext_vector_type(8))) unsigned short u16x8;
typedef __attribute__((ext_vector_type(4))) float f32x4;

// ---------------------------------------------------------------------------
// Fused init: deg[i]=1 + W split into bf16 hi/lo, PACKED IN FRAGMENT ORDER:
// packed index p = ((kk*8 + c)*64 + lane)*8 + j  <-  W[(c*16+(lane&15))*128
// + kk*32 + (lane>>4)*8 + j]. Wave B-fragment load = base + lane*16B.
__global__ __launch_bounds__(256) void init_split_kernel(
    int* __restrict__ deg, int N, const float* __restrict__ W,
    short* __restrict__ Wh, short* __restrict__ Wl, int n)
{
    int i = blockIdx.x * 256 + threadIdx.x;
    if (i < N) deg[i] = 1;
    if (i < n) {
        int l    = i >> 14;          // layer (0,1)
        int p    = i & 16383;
        int j    = p & 7;
        int lane = (p >> 3) & 63;
        int c    = (p >> 9) & 7;
        int kk   = p >> 12;
        int mr   = lane & 15;
        int quad = lane >> 4;
        int row  = c * 16 + mr;
        int d    = kk * 32 + quad * 8 + j;
        float f = W[(size_t)l * 16384 + row * 128 + d];
        unsigned short hi = f2bf(f);
        Wh[i] = (short)hi;
        Wl[i] = (short)f2bf(f - bf2f(hi));
    }
}

// Mext[r][d] per layer: r 0..3 = Wt@Al head r, r 4..7 = Wt@Ar, r 8..15 = 0.
__global__ __launch_bounds__(128) void mlr_prep_kernel(
    const float* __restrict__ fc_W, const float* __restrict__ attn_l,
    const float* __restrict__ attn_r, short* __restrict__ Mh,
    short* __restrict__ Ml)
{
    int l = blockIdx.x;                       // 0,1 -> layers 1,2
    const float* W  = fc_W + (size_t)(l + 1) * 16384;
    const float* al = attn_l + (l + 1) * 128;
    const float* ar = attn_r + (l + 1) * 128;
    short* mh = Mh + (size_t)l * 16 * 128;
    short* ml = Ml + (size_t)l * 16 * 128;
    int d = threadIdx.x;
#pragma unroll
    for (int r = 0; r < 8; ++r) {
        int hh = r & 3;
        const float* av = (r < 4) ? al : ar;
        float s = 0.f;
        for (int f = 0; f < 32; ++f)
            s += W[(size_t)(hh * 32 + f) * 128 + d] * av[hh * 32 + f];
        unsigned short hi = f2bf(s);
        mh[r * 128 + d] = (short)hi;
        ml[r * 128 + d] = (short)f2bf(s - bf2f(hi));
    }
#pragma unroll
    for (int r = 8; r < 16; ++r) { mh[r * 128 + d] = 0; ml[r * 128 + d] = 0; }
}

// slot[i] = old count (>=1 because self loop holds slot 0)
__global__ __launch_bounds__(256) void deg_count_slot_kernel(
    const int* __restrict__ dst, int* __restrict__ deg,
    int* __restrict__ slot, int E)
{
    int i = blockIdx.x * 256 + threadIdx.x;
    if (i < E) slot[i] = atomicAdd(&deg[dst[i]], 1);
}

#define SCAN_TILE 1024

__global__ __launch_bounds__(256) void scanA_kernel(
    const int* __restrict__ deg, int* __restrict__ bsum, int N)
{
    __shared__ int ws[4];
    int b = blockIdx.x, t = threadIdx.x;
    int base = b * SCAN_TILE + t * 4;
    int s = 0;
#pragma unroll
    for (int k = 0; k < 4; ++k) {
        int i = base + k;
        if (i < N) s += deg[i];
    }
#pragma unroll
    for (int m = 32; m >= 1; m >>= 1) s += __shfl_xor(s, m, 64);
    if ((t & 63) == 0) ws[t >> 6] = s;
    __syncthreads();
    if (t == 0) bsum[b] = ws[0] + ws[1] + ws[2] + ws[3];
}

__global__ __launch_bounds__(1024) void scanB_kernel(
    int* __restrict__ bsum, int* __restrict__ bpre, int* __restrict__ rowp,
    int NB, int N)
{
    __shared__ int sh[1024];
    int t = threadIdx.x;
    int v = (t < NB) ? bsum[t] : 0;
    sh[t] = v;
    __syncthreads();
    for (int off = 1; off < 1024; off <<= 1) {
        int u = (t >= off) ? sh[t - off] : 0;
        __syncthreads();
        sh[t] += u;
        __syncthreads();
    }
    if (t < NB) bpre[t] = sh[t] - v;          // exclusive prefix
    if (t == 1023) rowp[N] = sh[1023];        // total
}

// scanC also writes the self-loop entry: col[rowp[i]] = i (slot 0).
__global__ __launch_bounds__(256) void scanC_kernel(
    const int* __restrict__ deg, const int* __restrict__ bpre,
    int* __restrict__ rowp, int* __restrict__ col, int N)
{
    __shared__ int sh[256];
    int b = blockIdx.x, t = threadIdx.x;
    int base = b * SCAN_TILE + t * 4;
    int v[4];
#pragma unroll
    for (int k = 0; k < 4; ++k) {
        int i = base + k;
        v[k] = (i < N) ? deg[i] : 0;
    }
    int tsum = v[0] + v[1] + v[2] + v[3];
    sh[t] = tsum;
    __syncthreads();
    for (int off = 1; off < 256; off <<= 1) {
        int u = (t >= off) ? sh[t - off] : 0;
        __syncthreads();
        sh[t] += u;
        __syncthreads();
    }
    int pre = bpre[b] + sh[t] - tsum;
#pragma unroll
    for (int k = 0; k < 4; ++k) {
        int i = base + k;
        if (i < N) {
            rowp[i] = pre;
            col[pre] = i;   // self loop at slot 0
        }
        pre += v[k];
    }
}

// atomic-free scatter: position fully determined by rowp + recorded slot
__global__ __launch_bounds__(256) void scatter2_kernel(
    const int* __restrict__ src, const int* __restrict__ dst,
    const int* __restrict__ slot, const int* __restrict__ rowp,
    int* __restrict__ col, int E)
{
    int i = blockIdx.x * 256 + threadIdx.x;
    if (i < E) col[rowp[dst[i]] + slot[i]] = src[i];
}

// ---------------------------------------------------------------------------
// Layer-0 rank-1 precompute
__global__ __launch_bounds__(128) void rank1_prep_kernel(
    const float* __restrict__ lW, const float* __restrict__ lb,
    const float* __restrict__ W0, const float* __restrict__ al,
    const float* __restrict__ ar, float* __restrict__ c1,
    float* __restrict__ c2, float* __restrict__ prm)
{
    int j = threadIdx.x;
    float s1 = 0.f, s2 = 0.f;
    for (int d = 0; d < 128; ++d) {
        float wv = W0[j * 128 + d];
        s1 += lW[d] * wv;
        s2 += lb[d] * wv;
    }
    c1[j] = s1; c2[j] = s2;
    __shared__ float sh1[128], sh2[128], sh3[128], sh4[128];
    sh1[j] = s1 * al[j]; sh2[j] = s2 * al[j];
    sh3[j] = s1 * ar[j]; sh4[j] = s2 * ar[j];
    __syncthreads();
    if (j < 4) {
        float p = 0.f, q = 0.f, r = 0.f, s = 0.f;
        for (int f = 0; f < 32; ++f) {
            p += sh1[j * 32 + f]; q += sh2[j * 32 + f];
            r += sh3[j * 32 + f]; s += sh4[j * 32 + f];
        }
        prm[j] = p; prm[4 + j] = q; prm[8 + j] = r; prm[12 + j] = s;
    }
}

// h0 (bf16) = w[n]*c1[j] + c2[j]; el0/er0 from rank-1 params.
__global__ __launch_bounds__(256) void rank1_apply_kernel(
    const float* __restrict__ w, const float* __restrict__ c1,
    const float* __restrict__ c2, const float* __restrict__ prm,
    unsigned short* __restrict__ hb, float* __restrict__ el,
    float* __restrict__ er, int N)
{
    int i = blockIdx.x * 256 + threadIdx.x;
    int n = i >> 5, k = i & 31;
    if (n >= N) return;
    float wn = w[n];
    float4 a = *reinterpret_cast<const float4*>(&c1[k * 4]);
    float4 b = *reinterpret_cast<const float4*>(&c2[k * 4]);
    ushort4 o;
    o.x = f2bf(wn * a.x + b.x);
    o.y = f2bf(wn * a.y + b.y);
    o.z = f2bf(wn * a.z + b.z);
    o.w = f2bf(wn * a.w + b.w);
    *reinterpret_cast<ushort4*>(&hb[(size_t)n * 128 + k * 4]) = o;
    if (k == 0) {
        float4 pl = *reinterpret_cast<const float4*>(&prm[0]);
        float4 ql = *reinterpret_cast<const float4*>(&prm[4]);
        float4 pr = *reinterpret_cast<const float4*>(&prm[8]);
        float4 qr = *reinterpret_cast<const float4*>(&prm[12]);
        float4 e1 = make_float4(wn * pl.x + ql.x, wn * pl.y + ql.y,
                                wn * pl.z + ql.z, wn * pl.w + ql.w);
        float4 e2 = make_float4(wn * pr.x + qr.x, wn * pr.y + qr.y,
                                wn * pr.z + qr.z, wn * pr.w + qr.w);
        *reinterpret_cast<float4*>(&el[(size_t)n * 4]) = e1;
        *reinterpret_cast<float4*>(&er[(size_t)n * 4]) = e2;
    }
}

// ---------------------------------------------------------------------------
// MFMA bf16 GEMM (layers 1,2) + fused el/er tile — 32 rows/wave,
// FRAGMENT-PACKED W (every bh/bl load = base + lane*16B = one coalesced
// 1 KB transaction — the R21 winner). x stays row-major (R22's packed-x
// was neutral/negative: it traded gemm load coalescing for agg store
// scatter).
__global__ __launch_bounds__(256) void gemm_mfma_kernel(
    const unsigned short* __restrict__ xb, const short* __restrict__ Wh,
    const short* __restrict__ Wl, const short* __restrict__ Mh,
    const short* __restrict__ Ml, unsigned short* __restrict__ hb,
    float* __restrict__ el, float* __restrict__ er, int N)
{
    const int lane = threadIdx.x & 63;
    const int wv   = threadIdx.x >> 6;
    const int m0   = blockIdx.x * 128 + wv * 32;  // 32 rows per wave
    const int mr   = lane & 15;
    const int quad = lane >> 4;

    int r0 = m0 + mr;      if (r0 > N - 1) r0 = N - 1;   // clamped load rows
    int r1 = m0 + 16 + mr; if (r1 > N - 1) r1 = N - 1;
    const unsigned short* xp0 = xb + (size_t)r0 * 128 + quad * 8;
    const unsigned short* xp1 = xb + (size_t)r1 * 128 + quad * 8;

    f32x4 acc0[8], acc1[8], acce0, acce1;
#pragma unroll
    for (int c = 0; c < 8; ++c) {
        acc0[c] = (f32x4){0.f, 0.f, 0.f, 0.f};
        acc1[c] = (f32x4){0.f, 0.f, 0.f, 0.f};
    }
    acce0 = (f32x4){0.f, 0.f, 0.f, 0.f};
    acce1 = (f32x4){0.f, 0.f, 0.f, 0.f};

#pragma unroll
    for (int kk = 0; kk < 4; ++kk) {
        bf16x8 a0 = *reinterpret_cast<const bf16x8*>(xp0 + kk * 32);
        bf16x8 a1 = *reinterpret_cast<const bf16x8*>(xp1 + kk * 32);

        const int kb = kk * 32 + quad * 8;
        // packed W: fragment (kk,c) lives at ((kk*8+c)*64 + lane)*8
        bf16x8 bh[8], bl[8];
#pragma unroll
        for (int c = 0; c < 8; ++c) {
            const size_t wo = (size_t)((kk * 8 + c) * 64 + lane) * 8;
            bh[c] = *reinterpret_cast<const bf16x8*>(Wh + wo);
            bl[c] = *reinterpret_cast<const bf16x8*>(Wl + wo);
        }
        bf16x8 eh = *reinterpret_cast<const bf16x8*>(Mh + (size_t)mr * 128 + kb);
        bf16x8 eo = *reinterpret_cast<const bf16x8*>(Ml + (size_t)mr * 128 + kb);
#pragma unroll
        for (int c = 0; c < 8; ++c) {
            acc0[c] = __builtin_amdgcn_mfma_f32_16x16x32_bf16(a0, bh[c], acc0[c], 0, 0, 0);
            acc0[c] = __builtin_amdgcn_mfma_f32_16x16x32_bf16(a0, bl[c], acc0[c], 0, 0, 0);
            acc1[c] = __builtin_amdgcn_mfma_f32_16x16x32_bf16(a1, bh[c], acc1[c], 0, 0, 0);
            acc1[c] = __builtin_amdgcn_mfma_f32_16x16x32_bf16(a1, bl[c], acc1[c], 0, 0, 0);
        }
        acce0 = __builtin_amdgcn_mfma_f32_16x16x32_bf16(a0, eh, acce0, 0, 0, 0);
        acce0 = __builtin_amdgcn_mfma_f32_16x16x32_bf16(a0, eo, acce0, 0, 0, 0);
        acce1 = __builtin_amdgcn_mfma_f32_16x16x32_bf16(a1, eh, acce1, 0, 0, 0);
        acce1 = __builtin_amdgcn_mfma_f32_16x16x32_bf16(a1, eo, acce1, 0, 0, 0);
    }

#pragma unroll
    for (int i = 0; i < 4; ++i) {
        int rowA = m0 + quad * 4 + i;
        if (rowA < N) {
            unsigned short* hp = hb + (size_t)rowA * 128 + mr;
#pragma unroll
            for (int c = 0; c < 8; ++c) hp[c * 16] = f2bf(acc0[c][i]);
            if (mr < 4)       el[(size_t)rowA * 4 + mr]       = acce0[i];
            else if (mr < 8)  er[(size_t)rowA * 4 + (mr - 4)] = acce0[i];
        }
        int rowB = m0 + 16 + quad * 4 + i;
        if (rowB < N) {
            unsigned short* hp = hb + (size_t)rowB * 128 + mr;
#pragma unroll
            for (int c = 0; c < 8; ++c) hp[c * 16] = f2bf(acc1[c][i]);
            if (mr < 4)       el[(size_t)rowB * 4 + mr]       = acce1[i];
            else if (mr < 8)  er[(size_t)rowB * 4 + (mr - 4)] = acce1[i];
        }
    }
}

// ---------------------------------------------------------------------------
// SINGLE-PASS fused online-softmax aggregation + epilogue (R17 structure;
// at its random-gather latency floor).
__global__ __launch_bounds__(256) void agg_fused_kernel(
    const unsigned short* __restrict__ hb, const float* __restrict__ el,
    const float* __restrict__ er, const int* __restrict__ rowp,
    const int* __restrict__ col, const float* __restrict__ bias,
    unsigned short* __restrict__ xout, const float* __restrict__ pW,
    const float* __restrict__ pb, float* __restrict__ logits,
    int N, int last)
{
    const int lane = threadIdx.x & 63;
    const int q    = lane >> 4;
    const int l16  = lane & 15;
    const int v    = blockIdx.x * 16 + (threadIdx.x >> 6) * 4 + q;
    if (v >= N) return;   // reductions below stay within the 16-lane quarter

    const int r0 = rowp[v], r1 = rowp[v + 1];   // r1 > r0 (self loop)
    const int head = l16 >> 2;       // head for this lane's 8 features
    const int f0   = l16 * 8;        // feature base 0..120
    const float erq = er[(size_t)v * 4 + head];

    float m = -INFINITY, s = 0.f;
    float acc[8];
#pragma unroll
    for (int k = 0; k < 8; ++k) acc[k] = 0.f;

    // prime the pipeline with edge r0
    int   u_cur  = col[r0];
    float el_cur = el[(size_t)u_cur * 4 + head];
    u16x8 hv_cur = *reinterpret_cast<const u16x8*>(&hb[(size_t)u_cur * 128 + f0]);

    for (int j = r0; j < r1; ++j) {
        // issue next edge's loads before this edge's compute
        int jn = (j + 1 < r1) ? (j + 1) : j;
        int   u_nxt  = col[jn];
        float el_nxt = el[(size_t)u_nxt * 4 + head];
        u16x8 hv_nxt = *reinterpret_cast<const u16x8*>(&hb[(size_t)u_nxt * 128 + f0]);

        float e  = leaky02(el_cur + erq);
        float nm = fmaxf(m, e);
        float sc = __expf(m - nm);   // 0 on first edge (m=-inf)
        float p  = __expf(e - nm);
        s = s * sc + p;
#pragma unroll
        for (int k = 0; k < 8; ++k) acc[k] = acc[k] * sc + p * bf2f(hv_cur[k]);
        m = nm;

        u_cur = u_nxt; el_cur = el_nxt; hv_cur = hv_nxt;
    }
    const float is = 1.f / s;

    float4 b0 = *reinterpret_cast<const float4*>(&bias[f0]);
    float4 b1 = *reinterpret_cast<const float4*>(&bias[f0 + 4]);
    const float bb[8] = {b0.x, b0.y, b0.z, b0.w, b1.x, b1.y, b1.z, b1.w};

    if (last) {
        float4 p0 = *reinterpret_cast<const float4*>(&pW[f0]);
        float4 p1 = *reinterpret_cast<const float4*>(&pW[f0 + 4]);
        const float pp[8] = {p0.x, p0.y, p0.z, p0.w, p1.x, p1.y, p1.z, p1.w};
        float part = 0.f;
#pragma unroll
        for (int k = 0; k < 8; ++k) part += (acc[k] * is + bb[k]) * pp[k];
#pragma unroll
        for (int d = 1; d <= 8; d <<= 1) part += __shfl_xor(part, d, 64);
        if (l16 == 0) logits[v] = part + pb[0];
    } else {
        u16x8 o;
#pragma unroll
        for (int k = 0; k < 8; ++k) o[k] = f2bf(leaky01(acc[k] * is + bb[k]));
        *reinterpret_cast<u16x8*>(&xout[(size_t)v * 128 + f0]) = o;
    }
}

// ---------------------------------------------------------------------------
extern "C" void kernel_launch(void* const* d_in, const int* in_sizes, int n_in,
                              void* d_out, int out_size, void* d_ws, size_t ws_size,
                              hipStream_t stream)
{
    const float* weights = (const float*)d_in[0];
    const float* lin_W   = (const float*)d_in[1];
    const float* lin_b   = (const float*)d_in[2];
    const float* fc_W    = (const float*)d_in[3];
    const float* attn_l  = (const float*)d_in[4];
    const float* attn_r  = (const float*)d_in[5];
    const float* conv_b  = (const float*)d_in[6];
    const float* pred_W  = (const float*)d_in[7];
    const float* pred_b  = (const float*)d_in[8];
    const int*   src     = (const int*)d_in[9];
    const int*   dst     = (const int*)d_in[10];

    const int N = in_sizes[0];
    const int E = in_sizes[9];
    const int NB = (N + SCAN_TILE - 1) / SCAN_TILE;

    // workspace layout (16B-aligned sections)
    unsigned short* xb = (unsigned short*)d_ws;                    // N*128 bf16 (pre-activated)
    unsigned short* hb = xb + (size_t)N * 128;                     // N*128 bf16
    float* el  = (float*)(hb + (size_t)N * 128);                   // N*4
    float* er  = el + (size_t)N * 4;                               // N*4
    float* c1  = er + (size_t)N * 4;                               // 128
    float* c2  = c1 + 128;                                         // 128
    float* prm = c2 + 128;                                         // 16
    short* Whs = (short*)(prm + 16);                               // 2*16384 bf16 (packed)
    short* Wls = Whs + 2 * 16384;                                  // 2*16384 bf16 (packed)
    short* Mhs = Wls + 2 * 16384;                                  // 2*2048 bf16 (Mext hi)
    short* Mls = Mhs + 2 * 2048;                                   // 2*2048 bf16 (Mext lo)
    int*   deg  = (int*)(Mls + 2 * 2048);                          // N
    int*   rowp = deg + N;                                         // N+1
    int*   slot = rowp + (N + 1);                                  // E
    int*   col  = slot + E;                                        // E+N
    int*   bsum = col + (E + N);                                   // NB
    int*   bpre = bsum + NB;                                       // NB

    // CSR build + packed W split (fresh every call: ws is re-poisoned)
    init_split_kernel<<<(N + 255) / 256, 256, 0, stream>>>(
        deg, N, fc_W + 16384, Whs, Wls, 2 * 16384);
    mlr_prep_kernel<<<2, 128, 0, stream>>>(fc_W, attn_l, attn_r, Mhs, Mls);
    deg_count_slot_kernel<<<(E + 255) / 256, 256, 0, stream>>>(dst, deg, slot, E);
    scanA_kernel<<<NB, 256, 0, stream>>>(deg, bsum, N);
    scanB_kernel<<<1, 1024, 0, stream>>>(bsum, bpre, rowp, NB, N);
    scanC_kernel<<<NB, 256, 0, stream>>>(deg, bpre, rowp, col, N);
    scatter2_kernel<<<(E + 255) / 256, 256, 0, stream>>>(src, dst, slot, rowp, col, E);

    // Layer 0 via rank-1 identity
    rank1_prep_kernel<<<1, 128, 0, stream>>>(lin_W, lin_b, fc_W, attn_l, attn_r,
                                             c1, c2, prm);
    rank1_apply_kernel<<<((size_t)N * 32 + 255) / 256, 256, 0, stream>>>(
        weights, c1, c2, prm, hb, el, er, N);
    agg_fused_kernel<<<(N + 15) / 16, 256, 0, stream>>>(
        hb, el, er, rowp, col, conv_b, xb, pred_W, pred_b, (float*)d_out, N, 0);

    // Layers 1, 2 (MFMA bf16 gemm, 32 rows/wave, packed W, fused el/er)
    for (int l = 1; l < 3; ++l) {
        gemm_mfma_kernel<<<(N + 127) / 128, 256, 0, stream>>>(
            xb, Whs + (size_t)(l - 1) * 16384, Wls + (size_t)(l - 1) * 16384,
            Mhs + (size_t)(l - 1) * 2048, Mls + (size_t)(l - 1) * 2048,
            hb, el, er, N);
        agg_fused_kernel<<<(N + 15) / 16, 256, 0, stream>>>(
            hb, el, er, rowp, col, conv_b + l * 128, xb, pred_W, pred_b,
            (float*)d_out, N, l == 2 ? 1 : 0);
    }
}